// Round 1
// baseline (182.528 us; speedup 1.0000x reference)
//
#include <hip/hip_runtime.h>

#define BINS 30
#define NWAVES 4            // 256 threads / 64
#define BLOCK 256

// Pass 1: one sweep over preds/targets. Per element: g=|sigmoid(x)-t|,
// bin=min(int(g*30),29), bce=max(x,0)-x*t+log1p(exp(-|x|)).
// Accumulate per-bin {count, sum(bce)} into per-wave LDS histograms,
// then block-merge and atomicAdd to global ws.
__global__ __launch_bounds__(BLOCK) void ghm_pass1(
    const float4* __restrict__ preds4, const float4* __restrict__ targets4,
    long n4, long n_total,
    float* __restrict__ g_cnt, float* __restrict__ g_sum)
{
    __shared__ float s_cnt[NWAVES][BINS];
    __shared__ float s_sum[NWAVES][BINS];

    const int tid  = threadIdx.x;
    const int wave = tid >> 6;

    for (int i = tid; i < NWAVES * BINS; i += BLOCK) {
        (&s_cnt[0][0])[i] = 0.0f;
        (&s_sum[0][0])[i] = 0.0f;
    }
    __syncthreads();

    const long stride = (long)gridDim.x * BLOCK;
    for (long i = (long)blockIdx.x * BLOCK + tid; i < n4; i += stride) {
        float4 p = preds4[i];
        float4 t = targets4[i];
        #pragma unroll
        for (int j = 0; j < 4; ++j) {
            float x  = (&p.x)[j];
            float tt = (&t.x)[j];
            float ax = fabsf(x);
            float e  = expf(-ax);                       // exp(-|x|)
            float inv = 1.0f / (1.0f + e);
            float s  = (x >= 0.0f) ? inv : e * inv;     // sigmoid(x)
            float g  = fabsf(s - tt);
            int   b  = (int)(g * (float)BINS);
            b = (b > BINS - 1) ? BINS - 1 : b;
            float bce = fmaxf(x, 0.0f) - x * tt + log1pf(e);
            atomicAdd(&s_cnt[wave][b], 1.0f);
            atomicAdd(&s_sum[wave][b], bce);
        }
    }

    // scalar tail (n_total not multiple of 4) — handled by block 0
    long tail_start = n4 * 4;
    if (blockIdx.x == 0 && tail_start + tid < n_total) {
        const float* preds   = (const float*)preds4;
        const float* targets = (const float*)targets4;
        float x  = preds[tail_start + tid];
        float tt = targets[tail_start + tid];
        float ax = fabsf(x);
        float e  = expf(-ax);
        float inv = 1.0f / (1.0f + e);
        float s  = (x >= 0.0f) ? inv : e * inv;
        float g  = fabsf(s - tt);
        int   b  = (int)(g * (float)BINS);
        b = (b > BINS - 1) ? BINS - 1 : b;
        float bce = fmaxf(x, 0.0f) - x * tt + log1pf(e);
        atomicAdd(&s_cnt[wave][b], 1.0f);
        atomicAdd(&s_sum[wave][b], bce);
    }

    __syncthreads();

    // merge the per-wave copies; one global atomic per bin per block
    if (tid < BINS) {
        float c = 0.0f, sm = 0.0f;
        #pragma unroll
        for (int w = 0; w < NWAVES; ++w) { c += s_cnt[w][tid]; sm += s_sum[w][tid]; }
        if (c != 0.0f) {
            atomicAdd(&g_cnt[tid], c);
            atomicAdd(&g_sum[tid], sm);
        }
    }
}

// Pass 2: single wave. loss = (1/n) * sum_b S_b / (0.75*acc_b + 0.25*cnt_b)
// over populated bins; n = max(#populated, 1).
__global__ void ghm_final(const float* __restrict__ g_cnt,
                          const float* __restrict__ g_sum,
                          const float* __restrict__ acc_sum,
                          float* __restrict__ out)
{
    int lane = threadIdx.x;
    float val = 0.0f, nz = 0.0f;
    if (lane < BINS) {
        float c = g_cnt[lane];
        if (c > 0.0f) {
            float na = 0.75f * acc_sum[lane] + 0.25f * c;
            val = g_sum[lane] / na;
            nz  = 1.0f;
        }
    }
    #pragma unroll
    for (int m = 32; m >= 1; m >>= 1) {
        val += __shfl_xor(val, m);
        nz  += __shfl_xor(nz,  m);
    }
    if (lane == 0) out[0] = val / fmaxf(nz, 1.0f);
}

extern "C" void kernel_launch(void* const* d_in, const int* in_sizes, int n_in,
                              void* d_out, int out_size, void* d_ws, size_t ws_size,
                              hipStream_t stream)
{
    const float* preds   = (const float*)d_in[0];
    const float* targets = (const float*)d_in[1];
    const float* acc_sum = (const float*)d_in[2];

    float* ws_cnt = (float*)d_ws;        // [0, 30)
    float* ws_sum = ws_cnt + BINS;       // [30, 60)

    long n  = (long)in_sizes[0];
    long n4 = n / 4;

    // workspace is poisoned 0xAA once and never re-poisoned; zero it every call
    hipMemsetAsync(d_ws, 0, 2 * BINS * sizeof(float), stream);

    long want = (n4 + BLOCK - 1) / BLOCK;
    int blocks = (int)((want < 2048) ? (want > 1 ? want : 1) : 2048);

    ghm_pass1<<<blocks, BLOCK, 0, stream>>>((const float4*)preds,
                                            (const float4*)targets,
                                            n4, n, ws_cnt, ws_sum);
    ghm_final<<<1, 64, 0, stream>>>(ws_cnt, ws_sum, acc_sum, (float*)d_out);
}

// Round 2
// 178.423 us; speedup vs baseline: 1.0230x; 1.0230x over previous
//
#include <hip/hip_runtime.h>

#define BINS 30
#define NWAVES 4            // 256 threads / 64
#define BLOCK 256
#define COPIES (NWAVES * 4) // 4 lane-group sub-histograms per wave
#define HSTRIDE 61          // odd word stride -> banks fully spread

// Fast transcendentals: v_exp_f32 computes 2^x, v_log_f32 computes log2(x).
// |rel err| ~1 ulp, far inside the 1.7e-2 relative accuracy budget.
__device__ __forceinline__ float fast_exp2(float x) { return __builtin_amdgcn_exp2f(x); }
__device__ __forceinline__ float fast_log2(float x) { return __builtin_amdgcn_logf(x); }
__device__ __forceinline__ float fast_rcp(float x)  { return __builtin_amdgcn_rcpf(x); }

#define LOG2E 1.4426950408889634f
#define LN2   0.6931471805599453f

// Per element: e = exp(-|x|), d = 1+e
//   sigmoid(x) = x>=0 ? 1/d : 1 - 1/d
//   g   = |sigmoid - t|,  bin = min(int(g*30), 29)
//   bce = max(x,0) - x*t + ln(d)        [== log1p(exp(-|x|))]
__global__ __launch_bounds__(BLOCK) void ghm_pass1(
    const float4* __restrict__ preds4, const float4* __restrict__ targets4,
    long n4, long n_total,
    float* __restrict__ g_cnt, float* __restrict__ g_sum)
{
    __shared__ float hist[COPIES * HSTRIDE];

    const int tid  = threadIdx.x;
    const int wave = tid >> 6;
    const int copy = (wave << 2) | (tid & 3);     // 16 lanes share a copy
    float* __restrict__ h = &hist[copy * HSTRIDE];

    for (int i = tid; i < COPIES * HSTRIDE; i += BLOCK) hist[i] = 0.0f;
    __syncthreads();

    const long stride = (long)gridDim.x * BLOCK;
    for (long i = (long)blockIdx.x * BLOCK + tid; i < n4; i += stride) {
        float4 p = preds4[i];
        float4 t = targets4[i];
        #pragma unroll
        for (int j = 0; j < 4; ++j) {
            float x  = (&p.x)[j];
            float tt = (&t.x)[j];
            float ax = fabsf(x);
            float e  = fast_exp2(-ax * LOG2E);      // exp(-|x|)
            float d  = 1.0f + e;
            float inv = fast_rcp(d);
            float s  = (x >= 0.0f) ? inv : 1.0f - inv;
            float g  = fabsf(s - tt);
            int   b  = (int)(g * (float)BINS);
            b = (b > BINS - 1) ? BINS - 1 : b;
            float bce = fmaxf(x, 0.0f) - x * tt + fast_log2(d) * LN2;
            atomicAdd(&h[2 * b],     1.0f);
            atomicAdd(&h[2 * b + 1], bce);
        }
    }

    // scalar tail (n_total not multiple of 4) — handled by block 0
    long tail_start = n4 * 4;
    if (blockIdx.x == 0 && tail_start + tid < n_total) {
        const float* preds   = (const float*)preds4;
        const float* targets = (const float*)targets4;
        float x  = preds[tail_start + tid];
        float tt = targets[tail_start + tid];
        float ax = fabsf(x);
        float e  = fast_exp2(-ax * LOG2E);
        float d  = 1.0f + e;
        float inv = fast_rcp(d);
        float s  = (x >= 0.0f) ? inv : 1.0f - inv;
        float g  = fabsf(s - tt);
        int   b  = (int)(g * (float)BINS);
        b = (b > BINS - 1) ? BINS - 1 : b;
        float bce = fmaxf(x, 0.0f) - x * tt + fast_log2(d) * LN2;
        atomicAdd(&h[2 * b],     1.0f);
        atomicAdd(&h[2 * b + 1], bce);
    }

    __syncthreads();

    // merge the 16 copies; one global atomic per {cnt,sum} per bin per block
    if (tid < 2 * BINS) {
        float v = 0.0f;
        #pragma unroll
        for (int c = 0; c < COPIES; ++c) v += hist[c * HSTRIDE + tid];
        int b = tid >> 1;
        atomicAdd((tid & 1) ? &g_sum[b] : &g_cnt[b], v);
    }
}

// Finalize: loss = (1/n) * sum_b S_b / (0.75*acc_b + 0.25*cnt_b) over populated
// bins; n = max(#populated, 1).
__global__ void ghm_final(const float* __restrict__ g_cnt,
                          const float* __restrict__ g_sum,
                          const float* __restrict__ acc_sum,
                          float* __restrict__ out)
{
    int lane = threadIdx.x;
    float val = 0.0f, nz = 0.0f;
    if (lane < BINS) {
        float c = g_cnt[lane];
        if (c > 0.0f) {
            float na = 0.75f * acc_sum[lane] + 0.25f * c;
            val = g_sum[lane] / na;
            nz  = 1.0f;
        }
    }
    #pragma unroll
    for (int m = 32; m >= 1; m >>= 1) {
        val += __shfl_xor(val, m);
        nz  += __shfl_xor(nz,  m);
    }
    if (lane == 0) out[0] = val / fmaxf(nz, 1.0f);
}

extern "C" void kernel_launch(void* const* d_in, const int* in_sizes, int n_in,
                              void* d_out, int out_size, void* d_ws, size_t ws_size,
                              hipStream_t stream)
{
    const float* preds   = (const float*)d_in[0];
    const float* targets = (const float*)d_in[1];
    const float* acc_sum = (const float*)d_in[2];

    float* ws_cnt = (float*)d_ws;        // [0, 30)
    float* ws_sum = ws_cnt + BINS;       // [30, 60)

    long n  = (long)in_sizes[0];
    long n4 = n / 4;

    // workspace is poisoned 0xAA once and never re-poisoned; zero it every call
    hipMemsetAsync(d_ws, 0, 2 * BINS * sizeof(float), stream);

    long want = (n4 + BLOCK - 1) / BLOCK;
    int blocks = (int)((want < 2048) ? (want > 1 ? want : 1) : 2048);

    ghm_pass1<<<blocks, BLOCK, 0, stream>>>((const float4*)preds,
                                            (const float4*)targets,
                                            n4, n, ws_cnt, ws_sum);
    ghm_final<<<1, 64, 0, stream>>>(ws_cnt, ws_sum, acc_sum, (float*)d_out);
}

// Round 3
// 177.562 us; speedup vs baseline: 1.0280x; 1.0048x over previous
//
#include <hip/hip_runtime.h>

#define BINS 30
#define NWAVES 4            // 256 threads / 64
#define BLOCK 256
#define COPIES (NWAVES * 4) // 4 lane-group sub-histograms per wave
#define HSTRIDE 61          // odd word stride -> banks fully spread
#define GSTRIDE 32          // global accumulator: one 128B line per slot

// v_exp_f32 (2^x), v_log_f32 (log2), v_rcp_f32 — ~1 ulp, far inside budget.
__device__ __forceinline__ float fast_exp2(float x) { return __builtin_amdgcn_exp2f(x); }
__device__ __forceinline__ float fast_log2(float x) { return __builtin_amdgcn_logf(x); }
__device__ __forceinline__ float fast_rcp(float x)  { return __builtin_amdgcn_rcpf(x); }

#define LOG2E 1.4426950408889634f
#define LN2   0.6931471805599453f

// Per element: e = exp(-|x|), d = 1+e
//   sigmoid(x) = x>=0 ? 1/d : 1 - 1/d
//   g   = |sigmoid - t|,  bin = min(int(g*30), 29)
//   bce = max(x,0) - x*t + ln(d)
// Per-block LDS histogram (16 copies), then ONE padded global atomic per
// {cnt,sum} word per block — each slot in its own 128B cache line so the
// memory-side atomic units work in parallel instead of serializing on 2 lines.
__global__ __launch_bounds__(BLOCK) void ghm_pass1(
    const float4* __restrict__ preds4, const float4* __restrict__ targets4,
    long n4, long n_total,
    float* __restrict__ g_acc)   // [2*BINS slots, stride GSTRIDE floats]
{
    __shared__ float hist[COPIES * HSTRIDE];

    const int tid  = threadIdx.x;
    const int wave = tid >> 6;
    const int copy = (wave << 2) | (tid & 3);     // 16 lanes share a copy
    float* __restrict__ h = &hist[copy * HSTRIDE];

    for (int i = tid; i < COPIES * HSTRIDE; i += BLOCK) hist[i] = 0.0f;
    __syncthreads();

    const long stride = (long)gridDim.x * BLOCK;
    for (long i = (long)blockIdx.x * BLOCK + tid; i < n4; i += stride) {
        float4 p = preds4[i];
        float4 t = targets4[i];
        #pragma unroll
        for (int j = 0; j < 4; ++j) {
            float x  = (&p.x)[j];
            float tt = (&t.x)[j];
            float ax = fabsf(x);
            float e  = fast_exp2(-ax * LOG2E);      // exp(-|x|)
            float d  = 1.0f + e;
            float inv = fast_rcp(d);
            float s  = (x >= 0.0f) ? inv : 1.0f - inv;
            float g  = fabsf(s - tt);
            int   b  = (int)(g * (float)BINS);
            b = (b > BINS - 1) ? BINS - 1 : b;
            float bce = fmaxf(x, 0.0f) - x * tt + fast_log2(d) * LN2;
            atomicAdd(&h[2 * b],     1.0f);
            atomicAdd(&h[2 * b + 1], bce);
        }
    }

    // scalar tail (n_total not multiple of 4) — handled by block 0
    long tail_start = n4 * 4;
    if (blockIdx.x == 0 && tail_start + tid < n_total) {
        const float* preds   = (const float*)preds4;
        const float* targets = (const float*)targets4;
        float x  = preds[tail_start + tid];
        float tt = targets[tail_start + tid];
        float ax = fabsf(x);
        float e  = fast_exp2(-ax * LOG2E);
        float d  = 1.0f + e;
        float inv = fast_rcp(d);
        float s  = (x >= 0.0f) ? inv : 1.0f - inv;
        float g  = fabsf(s - tt);
        int   b  = (int)(g * (float)BINS);
        b = (b > BINS - 1) ? BINS - 1 : b;
        float bce = fmaxf(x, 0.0f) - x * tt + fast_log2(d) * LN2;
        atomicAdd(&h[2 * b],     1.0f);
        atomicAdd(&h[2 * b + 1], bce);
    }

    __syncthreads();

    // merge the 16 copies; 60 global atomics per block, each to its OWN line
    if (tid < 2 * BINS) {
        float v = 0.0f;
        #pragma unroll
        for (int c = 0; c < COPIES; ++c) v += hist[c * HSTRIDE + tid];
        atomicAdd(&g_acc[tid * GSTRIDE], v);
    }
}

// Finalize: slot 2b = cnt_b, slot 2b+1 = sum_b (each GSTRIDE floats apart).
// loss = (1/n) * sum_b S_b / (0.75*acc_b + 0.25*cnt_b), n = max(#populated,1)
__global__ void ghm_final(const float* __restrict__ g_acc,
                          const float* __restrict__ acc_sum,
                          float* __restrict__ out)
{
    int lane = threadIdx.x;
    float val = 0.0f, nz = 0.0f;
    if (lane < BINS) {
        float c = g_acc[(2 * lane) * GSTRIDE];
        if (c > 0.0f) {
            float sm = g_acc[(2 * lane + 1) * GSTRIDE];
            float na = 0.75f * acc_sum[lane] + 0.25f * c;
            val = sm / na;
            nz  = 1.0f;
        }
    }
    #pragma unroll
    for (int m = 32; m >= 1; m >>= 1) {
        val += __shfl_xor(val, m);
        nz  += __shfl_xor(nz,  m);
    }
    if (lane == 0) out[0] = val / fmaxf(nz, 1.0f);
}

extern "C" void kernel_launch(void* const* d_in, const int* in_sizes, int n_in,
                              void* d_out, int out_size, void* d_ws, size_t ws_size,
                              hipStream_t stream)
{
    const float* preds   = (const float*)d_in[0];
    const float* targets = (const float*)d_in[1];
    const float* acc_sum = (const float*)d_in[2];

    float* g_acc = (float*)d_ws;   // 2*BINS slots x GSTRIDE floats = 7680 B

    long n  = (long)in_sizes[0];
    long n4 = n / 4;

    // ws is poisoned once and never re-poisoned; zero the slots every call
    hipMemsetAsync(d_ws, 0, 2 * BINS * GSTRIDE * sizeof(float), stream);

    long want = (n4 + BLOCK - 1) / BLOCK;
    int blocks = (int)((want < 1024) ? (want > 1 ? want : 1) : 1024);

    ghm_pass1<<<blocks, BLOCK, 0, stream>>>((const float4*)preds,
                                            (const float4*)targets,
                                            n4, n, g_acc);
    ghm_final<<<1, 64, 0, stream>>>(g_acc, acc_sum, (float*)d_out);
}

// Round 4
// 88.820 us; speedup vs baseline: 2.0550x; 1.9991x over previous
//
#include <hip/hip_runtime.h>

#define BINS 30
#define BLOCK 256
#define GRID 2048
#define GSTRIDE 32   // one 128B cache line per global accumulator slot

__device__ __forceinline__ float fast_exp2(float x){ return __builtin_amdgcn_exp2f(x); }
__device__ __forceinline__ float fast_log2(float x){ return __builtin_amdgcn_logf(x); }

#define LOG2E 1.4426950408889634f
#define LN2   0.6931471805599453f

// Thresholds c_k = logit(k/30) = ln(k/(30-k)), k=1..29.
// bin(y) = #{k : y >= c_k};  g = sigmoid(y);  bce = softplus(y).
#define THRESH_LIST { \
    -3.3673323f, -2.6390573f, -2.1972246f, -1.8718022f, -1.6094379f, \
    -1.3862944f, -1.1895841f, -1.0116009f, -0.8472979f, -0.6931472f, \
    -0.5465437f, -0.4054651f, -0.2682640f, -0.1335314f,  0.0f,       \
     0.1335314f,  0.2682640f,  0.4054651f,  0.5465437f,  0.6931472f, \
     0.8472979f,  1.0116009f,  1.1895841f,  1.3862944f,  1.6094379f, \
     1.8718022f,  2.1972246f,  2.6390573f,  3.3673323f }

// Per element: y = t ? -x : x.  Accumulate per-lane CUMULATIVE stats in
// registers (statically indexed -> stays in VGPRs):
//   scnt[k] += (y >= c[k+1])          k=0..28   (cnt-cumsum, C_1..C_29)
//   ssum[0] += bce                              (S-cumsum S_0 = total)
//   ssum[k+1] += (y >= c[k+1]) ? bce : 0        (S_1..S_29)
// NO LDS ops and NO atomics in the hot loop.
__global__ __launch_bounds__(BLOCK) void ghm_pass1(
    const float4* __restrict__ preds4, const float4* __restrict__ targets4,
    long n4, long n_total,
    float* __restrict__ gS,        // slots 0..29, stride GSTRIDE floats
    unsigned* __restrict__ gC)     // slots 0..28, stride GSTRIDE uints
{
    const float c[29] = THRESH_LIST;

    float    ssum[30];
    unsigned scnt[29];
    #pragma unroll
    for (int i = 0; i < 30; ++i) ssum[i] = 0.0f;
    #pragma unroll
    for (int i = 0; i < 29; ++i) scnt[i] = 0u;

    const int tid = threadIdx.x;
    const long stride = (long)gridDim.x * BLOCK;
    for (long i = (long)blockIdx.x * BLOCK + tid; i < n4; i += stride) {
        float4 p = preds4[i];
        float4 t = targets4[i];
        #pragma unroll
        for (int j = 0; j < 4; ++j) {
            float x  = (&p.x)[j];
            float tt = (&t.x)[j];
            float y  = (tt != 0.0f) ? -x : x;
            float e  = fast_exp2(-fabsf(y) * LOG2E);        // exp(-|y|)
            float bce = fmaxf(y, 0.0f) + fast_log2(1.0f + e) * LN2; // softplus(y)
            ssum[0] += bce;
            #pragma unroll
            for (int k = 0; k < 29; ++k) {
                bool pgt = (y >= c[k]);
                scnt[k]     += pgt ? 1u : 0u;     // v_cmp + v_addc
                ssum[k + 1] += pgt ? bce : 0.0f;  // v_cndmask + v_add
            }
        }
    }

    // tail (n_total not multiple of 4): wave 0 of block 0, predicated so the
    // same cumulative accumulators absorb it (y=-inf-ish => contributes 0)
    long tail0 = n4 * 4;
    int  ntail = (int)(n_total - tail0);
    if (ntail > 0 && blockIdx.x == 0 && tid < 64) {
        bool  act = tid < ntail;
        float x   = act ? ((const float*)preds4)[tail0 + tid]   : 0.0f;
        float tt  = act ? ((const float*)targets4)[tail0 + tid] : 0.0f;
        float y   = (tt != 0.0f) ? -x : x;
        if (!act) y = -1e30f;
        float e   = fast_exp2(-fabsf(y) * LOG2E);
        float bce = act ? (fmaxf(y, 0.0f) + fast_log2(1.0f + e) * LN2) : 0.0f;
        ssum[0] += bce;
        #pragma unroll
        for (int k = 0; k < 29; ++k) {
            bool pgt = (y >= c[k]);
            scnt[k]     += pgt ? 1u : 0u;
            ssum[k + 1] += pgt ? bce : 0.0f;
        }
    }

    // ---- merge: wave butterfly, then lane0-only LDS atomics, then one
    // padded global atomic per slot per block ----
    __shared__ float    lS[30];
    __shared__ unsigned lC[29];
    for (int i = tid; i < 30; i += BLOCK) lS[i] = 0.0f;
    for (int i = tid; i < 29; i += BLOCK) lC[i] = 0u;
    __syncthreads();

    const int lane = tid & 63;
    #pragma unroll
    for (int i = 0; i < 30; ++i) {
        float v = ssum[i];
        #pragma unroll
        for (int m = 32; m >= 1; m >>= 1) v += __shfl_xor(v, m);
        if (lane == 0) atomicAdd(&lS[i], v);
    }
    #pragma unroll
    for (int i = 0; i < 29; ++i) {
        unsigned v = scnt[i];
        #pragma unroll
        for (int m = 32; m >= 1; m >>= 1) v += __shfl_xor(v, m);
        if (lane == 0) atomicAdd(&lC[i], v);
    }
    __syncthreads();

    if (tid < 30) atomicAdd(&gS[tid * GSTRIDE], lS[tid]);
    if (tid < 29) atomicAdd(&gC[tid * GSTRIDE], lC[tid]);
}

// Finalize (one wave): cnt_b = C_b - C_{b+1} (C_0 = tot, C_30 = 0),
// S_b = Scum_b - Scum_{b+1} (Scum_30 = 0).
// loss = (1/n) * sum_b S_b / (0.75*acc_b + 0.25*cnt_b) over populated bins.
__global__ void ghm_final(const float* __restrict__ gS,
                          const unsigned* __restrict__ gC,
                          const float* __restrict__ acc_sum,
                          float* __restrict__ out, float tot)
{
    int b = threadIdx.x;
    float val = 0.0f, nz = 0.0f;
    if (b < BINS) {
        float Cb  = (b == 0)  ? tot  : (float)gC[(b - 1) * GSTRIDE];
        float Cb1 = (b == 29) ? 0.0f : (float)gC[b * GSTRIDE];
        float cnt = Cb - Cb1;
        if (cnt > 0.0f) {
            float Sb = gS[b * GSTRIDE] - ((b == 29) ? 0.0f : gS[(b + 1) * GSTRIDE]);
            float na = 0.75f * acc_sum[b] + 0.25f * cnt;
            val = Sb / na;
            nz  = 1.0f;
        }
    }
    #pragma unroll
    for (int m = 32; m >= 1; m >>= 1) {
        val += __shfl_xor(val, m);
        nz  += __shfl_xor(nz,  m);
    }
    if (b == 0) out[0] = val / fmaxf(nz, 1.0f);
}

extern "C" void kernel_launch(void* const* d_in, const int* in_sizes, int n_in,
                              void* d_out, int out_size, void* d_ws, size_t ws_size,
                              hipStream_t stream)
{
    const float* preds   = (const float*)d_in[0];
    const float* targets = (const float*)d_in[1];
    const float* acc_sum = (const float*)d_in[2];

    float*    gS = (float*)d_ws;                        // slots 0..29
    unsigned* gC = (unsigned*)(gS + 30 * GSTRIDE);      // slots 0..28

    long n  = (long)in_sizes[0];
    long n4 = n / 4;

    // ws poisoned once, never re-poisoned: zero accumulators every call
    hipMemsetAsync(d_ws, 0, 59 * GSTRIDE * sizeof(float), stream);

    long want = (n4 + BLOCK - 1) / BLOCK;
    int blocks = (int)((want < GRID) ? (want > 1 ? want : 1) : GRID);

    ghm_pass1<<<blocks, BLOCK, 0, stream>>>((const float4*)preds,
                                            (const float4*)targets,
                                            n4, n, gS, gC);
    ghm_final<<<1, 64, 0, stream>>>(gS, gC, acc_sum, (float*)d_out, (float)n);
}

// Round 5
// 36.639 us; speedup vs baseline: 4.9818x; 2.4242x over previous
//
#include <hip/hip_runtime.h>

#define BINS 30
#define BLOCK 256
#define GRID 512            // 2 blocks/CU (60 KB LDS each) x 256 CU = one round
#define GSTRIDE 32          // one 128B cache line per global accumulator slot

__device__ __forceinline__ float fast_exp2(float x){ return __builtin_amdgcn_exp2f(x); }
__device__ __forceinline__ float fast_log2(float x){ return __builtin_amdgcn_logf(x); }
__device__ __forceinline__ float fast_rcp (float x){ return __builtin_amdgcn_rcpf(x); }

#define LOG2E 1.4426950408889634f
#define LN2   0.6931471805599453f

// Per element: y = (t?-x:x) = x - 2*t*x  (t in {0,1} exactly)
//   g   = sigmoid(y)  (== |sigmoid(x)-t|),  bin = min(int(g*30), 29)
//   bce = max(y,0) + log1p(exp(-|y|))      (== stable BCE-with-logits)
// Accumulate {cnt,sum} into a THREAD-PRIVATE LDS column hist[bin][tid]:
// plain ds_read_b64/ds_write_b64 RMW — no atomics, no per-lane serialization,
// race-free because only thread `tid` ever touches column `tid`.
__global__ __launch_bounds__(BLOCK) void ghm_pass1(
    const float4* __restrict__ preds4, const float4* __restrict__ targets4,
    long n4, long n_total,
    float* __restrict__ gCnt, float* __restrict__ gSum)  // padded slots
{
    __shared__ float2 hist[BINS][BLOCK];   // 60 KB: {cnt, sum} per bin per thread

    const int tid = threadIdx.x;
    #pragma unroll
    for (int b = 0; b < BINS; ++b) hist[b][tid] = make_float2(0.0f, 0.0f);
    __syncthreads();

    auto do4 = [&](float4 p, float4 t) {
        #pragma unroll
        for (int j = 0; j < 4; ++j) {
            float x  = (&p.x)[j];
            float tt = (&t.x)[j];
            float y  = __builtin_fmaf(x * tt, -2.0f, x);   // t ? -x : x
            float e  = fast_exp2(fabsf(y) * -LOG2E);       // exp(-|y|)
            float d  = 1.0f + e;
            float r  = fast_rcp(d);
            float g  = (y >= 0.0f) ? r : e * r;            // sigmoid(y)
            int   b  = (int)(g * 30.0f);
            b = (b > BINS - 1) ? BINS - 1 : b;
            float bce = fmaxf(y, 0.0f) + fast_log2(d) * LN2;
            float2 h = hist[b][tid];
            h.x += 1.0f;
            h.y += bce;
            hist[b][tid] = h;
        }
    };

    const long stride = (long)gridDim.x * BLOCK;
    long i = (long)blockIdx.x * BLOCK + tid;
    // 2x manual unroll for memory-level parallelism
    for (; i + stride < n4; i += 2 * stride) {
        float4 p0 = preds4[i];
        float4 t0 = targets4[i];
        float4 p1 = preds4[i + stride];
        float4 t1 = targets4[i + stride];
        do4(p0, t0);
        do4(p1, t1);
    }
    for (; i < n4; i += stride) {
        do4(preds4[i], targets4[i]);
    }

    // scalar tail (n_total % 4) — block 0, predicated, same private columns
    long tail0 = n4 * 4;
    if (blockIdx.x == 0 && tail0 + tid < n_total) {
        float x  = ((const float*)preds4)[tail0 + tid];
        float tt = ((const float*)targets4)[tail0 + tid];
        float y  = __builtin_fmaf(x * tt, -2.0f, x);
        float e  = fast_exp2(fabsf(y) * -LOG2E);
        float d  = 1.0f + e;
        float r  = fast_rcp(d);
        float g  = (y >= 0.0f) ? r : e * r;
        int   b  = (int)(g * 30.0f);
        b = (b > BINS - 1) ? BINS - 1 : b;
        float bce = fmaxf(y, 0.0f) + fast_log2(d) * LN2;
        float2 h = hist[b][tid];
        h.x += 1.0f; h.y += bce;
        hist[b][tid] = h;
    }
    __syncthreads();

    // tree-reduce 256 columns -> column 0 (s = 128..1, power of two)
    for (int k = 7; k >= 0; --k) {
        int s = 1 << k;
        for (int i2 = tid; i2 < (BINS << k); i2 += BLOCK) {
            int b = i2 >> k;
            int c = i2 & (s - 1);
            float2 a  = hist[b][c];
            float2 d2 = hist[b][c + s];
            hist[b][c] = make_float2(a.x + d2.x, a.y + d2.y);
        }
        __syncthreads();
    }

    // one padded global atomic per {cnt,sum} per bin per block
    if (tid < BINS) {
        float2 h = hist[tid][0];
        if (h.x != 0.0f) {
            atomicAdd(&gCnt[tid * GSTRIDE], h.x);
            atomicAdd(&gSum[tid * GSTRIDE], h.y);
        }
    }
}

// loss = (1/n) * sum_b S_b / (0.75*acc_b + 0.25*cnt_b) over populated bins,
// n = max(#populated, 1)
__global__ void ghm_final(const float* __restrict__ gCnt,
                          const float* __restrict__ gSum,
                          const float* __restrict__ acc_sum,
                          float* __restrict__ out)
{
    int b = threadIdx.x;
    float val = 0.0f, nz = 0.0f;
    if (b < BINS) {
        float c = gCnt[b * GSTRIDE];
        if (c > 0.0f) {
            float na = 0.75f * acc_sum[b] + 0.25f * c;
            val = gSum[b * GSTRIDE] / na;
            nz  = 1.0f;
        }
    }
    #pragma unroll
    for (int m = 32; m >= 1; m >>= 1) {
        val += __shfl_xor(val, m);
        nz  += __shfl_xor(nz,  m);
    }
    if (b == 0) out[0] = val / fmaxf(nz, 1.0f);
}

extern "C" void kernel_launch(void* const* d_in, const int* in_sizes, int n_in,
                              void* d_out, int out_size, void* d_ws, size_t ws_size,
                              hipStream_t stream)
{
    const float* preds   = (const float*)d_in[0];
    const float* targets = (const float*)d_in[1];
    const float* acc_sum = (const float*)d_in[2];

    float* gCnt = (float*)d_ws;                 // slots 0..29, stride GSTRIDE
    float* gSum = gCnt + BINS * GSTRIDE;        // slots 0..29, stride GSTRIDE

    long n  = (long)in_sizes[0];
    long n4 = n / 4;

    // ws poisoned once, never re-poisoned: zero accumulators every call
    hipMemsetAsync(d_ws, 0, 2 * BINS * GSTRIDE * sizeof(float), stream);

    long want = (n4 + BLOCK - 1) / BLOCK;
    int blocks = (int)((want < GRID) ? (want > 1 ? want : 1) : GRID);

    ghm_pass1<<<blocks, BLOCK, 0, stream>>>((const float4*)preds,
                                            (const float4*)targets,
                                            n4, n, gCnt, gSum);
    ghm_final<<<1, 64, 0, stream>>>(gCnt, gSum, acc_sum, (float*)d_out);
}